// Round 4
// baseline (1544.312 us; speedup 1.0000x reference)
//
#include <hip/hip_runtime.h>
#include <hip/hip_bf16.h>
#include <math.h>

typedef float f4 __attribute__((ext_vector_type(4)));
typedef float f32x4 __attribute__((ext_vector_type(4)));
typedef _Float16 h4 __attribute__((ext_vector_type(4)));
typedef _Float16 h8 __attribute__((ext_vector_type(8)));

#define D_ 1024
#define DFF_ 4096
#define L_ 2
#define RF_ 16
#define NTOK_ 1152            // B * NC = 32*36
#define M_ 18432              // NTOK_ * RF_

__device__ __forceinline__ void gload_lds16(const void* g, void* l) {
  __builtin_amdgcn_global_load_lds((const __attribute__((address_space(1))) void*)g,
                                   (__attribute__((address_space(3))) void*)l, 16, 0, 0);
}

// exact-GELU via A&S 7.1.26 erf poly (|err| <= 1.5e-7), ~12 VALU + v_exp vs libm erff
__device__ __forceinline__ float gelu_f(float x) {
  float z = fabsf(x) * 0.70710678118654752f;
  float t = 1.0f / (1.0f + 0.3275911f * z);
  float poly = t * (0.254829592f + t * (-0.284496736f + t * (1.421413741f +
               t * (-1.453152027f + t * 1.061405429f))));
  float erfz = 1.0f - poly * __expf(-z * z);
  erfz = copysignf(erfz, x);
  return 0.5f * x * (1.0f + erfz);
}

// ---------------- elementwise ----------------
__global__ __launch_bounds__(256) void k_init_x(float* __restrict__ x, const float* __restrict__ rfq) {
  int i = blockIdx.x * 256 + threadIdx.x;   // float4 index
  int c = i & 255;                          // D/4 = 256
  int m = i >> 8;
  ((f4*)x)[i] = ((const f4*)rfq)[((m & 15) << 8) | c];   // row m -> rf row m%16
}

__global__ __launch_bounds__(256) void k_cvt(const float* __restrict__ in, _Float16* __restrict__ out) {
  int i = blockIdx.x * 256 + threadIdx.x;
  f4 v = ((const f4*)in)[i];
  ((h4*)out)[i] = __builtin_convertvector(v, h4);
}

__global__ __launch_bounds__(256) void k_bcast_add(float* __restrict__ x, const float* __restrict__ att) {
  int i = blockIdx.x * 256 + threadIdx.x;
  int c = i & 255;
  int m = i >> 8;
  int n = m >> 4;                           // m / RF
  f4 v = ((f4*)x)[i];
  f4 a = ((const f4*)att)[(n << 8) | c];
  ((f4*)x)[i] = v + a;
}

// W (R x C, f32, row-major) -> WT (C x R, f16)
__global__ __launch_bounds__(256) void k_transpose_cvt(const float* __restrict__ W, _Float16* __restrict__ WT,
                                                       int R, int C) {
  __shared__ float t[32][33];
  int c0 = blockIdx.x * 32, r0 = blockIdx.y * 32;
  int cc = threadIdx.x & 31, rr = threadIdx.x >> 5;   // rr: 0..7
  #pragma unroll
  for (int p = 0; p < 32; p += 8)
    t[rr + p][cc] = W[(size_t)(r0 + rr + p) * C + (c0 + cc)];
  __syncthreads();
  #pragma unroll
  for (int p = 0; p < 32; p += 8)
    WT[(size_t)(c0 + rr + p) * R + (r0 + cc)] = (_Float16)t[cc][rr + p];
}

// ---------------- layernorm ----------------
__device__ inline float block_sum256(float v) {
  __shared__ float red[4];
  #pragma unroll
  for (int o = 32; o > 0; o >>= 1) v += __shfl_down(v, o);
  int w = threadIdx.x >> 6;
  if ((threadIdx.x & 63) == 0) red[w] = v;
  __syncthreads();
  float r = red[0] + red[1] + red[2] + red[3];
  __syncthreads();
  return r;
}

template<int F16OUT>
__global__ __launch_bounds__(256) void k_ln(const float* __restrict__ x, const float* __restrict__ s,
                                            const float* __restrict__ b, void* __restrict__ out) {
  size_t row = blockIdx.x;
  int t = threadIdx.x;
  f4 v = ((const f4*)(x + row * D_))[t];
  float mean = block_sum256(v.x + v.y + v.z + v.w) * (1.0f / D_);
  f4 d = v - mean;
  float var = block_sum256(d.x*d.x + d.y*d.y + d.z*d.z + d.w*d.w) * (1.0f / D_);
  float rstd = rsqrtf(var + 1e-5f);
  f4 sc = ((const f4*)s)[t];
  f4 bb = ((const f4*)b)[t];
  f4 r = d * rstd * sc + bb;
  if (F16OUT) ((h4*)out)[row * (D_/4) + t] = __builtin_convertvector(r, h4);
  else        ((f4*)out)[row * (D_/4) + t] = r;
}

// ---------------- GEMM:  C(MxN) = A(MxK,f16) @ Bt(NxK,f16)^T + bias ----------------
// 2-phase double-buffered pipeline (T3-minimum recipe): STAGE(next -> other buf)
// issued BEFORE compute(cur); one vmcnt(0) + raw s_barrier per K-tile so the
// HBM latency of next-tile loads overlaps this tile's ds_read+MFMA.
// Both-sides XOR swizzle (16B slot ^= row&7): proven 0 bank conflicts (round 3).
// EPI: 0 -> f16 store, 1 -> f32 store, 2 -> gelu f16 store, 3 -> += into f32
template<int EPI>
__global__ __launch_bounds__(256) void k_gemm(const _Float16* __restrict__ A,
                                              const _Float16* __restrict__ Bt,
                                              const float* __restrict__ bias,
                                              void* __restrict__ out,
                                              int M, int N, int K) {
  __shared__ __align__(16) _Float16 As[2][128][64];
  __shared__ __align__(16) _Float16 Bs[2][128][64];
  const int tid = threadIdx.x;
  const int lane = tid & 63;
  const int w = tid >> 6;

  // T1: XCD chunked-contiguous block swizzle (all our grids have nwg % 8 == 0)
  const unsigned gdx = gridDim.x;
  const unsigned nwg = gdx * gridDim.y;
  unsigned bid = blockIdx.y * gdx + blockIdx.x;
  if ((nwg & 7u) == 0u) bid = (bid & 7u) * (nwg >> 3) + (bid >> 3);
  const int bm = (int)(bid / gdx) << 7;
  const int bn = (int)(bid % gdx) << 7;

  const int wr = (w >> 1) << 6;       // wave row offset in tile (0/64)
  const int wc = (w & 1) << 6;        // wave col offset (0/64)
  const int g = lane >> 4;            // 0..3
  const int lr = lane & 15;
  const int x7 = lr & 7;              // read-side swizzle key (row&7 == lr&7)
  const int srow = lane >> 3;         // staging row within 8-row group
  const int scl8 = (((lane & 7) ^ (srow & 7)) << 3);   // inverse-swizzled src col (halves)

  f32x4 acc[4][4];
  #pragma unroll
  for (int m = 0; m < 4; ++m)
    #pragma unroll
    for (int n = 0; n < 4; ++n)
      acc[m][n] = (f32x4){0.f, 0.f, 0.f, 0.f};

  const _Float16* Ab = A + (size_t)bm * K;
  const _Float16* Bb = Bt + (size_t)bn * K;

  auto stage = [&](int buf, int kt) {
    #pragma unroll
    for (int p = 0; p < 4; ++p) {
      int r0 = ((w << 2) + p) << 3;                    // wave-uniform LDS base row
      int r = r0 + srow;
      gload_lds16(Ab + (size_t)r * K + kt + scl8, &As[buf][r0][0]);
      gload_lds16(Bb + (size_t)r * K + kt + scl8, &Bs[buf][r0][0]);
    }
  };
  auto compute = [&](int buf) {
    #pragma unroll
    for (int kk8 = 0; kk8 < 8; kk8 += 4) {             // two K=32 sub-steps
      h8 af[4], bf[4];
      const int c8 = ((kk8 + g) ^ x7) << 3;            // swizzled read slot (halves)
      #pragma unroll
      for (int m = 0; m < 4; ++m) af[m] = *(const h8*)(&As[buf][wr + (m << 4) + lr][c8]);
      #pragma unroll
      for (int n = 0; n < 4; ++n) bf[n] = *(const h8*)(&Bs[buf][wc + (n << 4) + lr][c8]);
      #pragma unroll
      for (int m = 0; m < 4; ++m)
        #pragma unroll
        for (int n = 0; n < 4; ++n)
          acc[m][n] = __builtin_amdgcn_mfma_f32_16x16x32_f16(af[m], bf[n], acc[m][n], 0, 0, 0);
    }
  };

  const int NT = K >> 6;                               // K-tiles (always even: K=1024/4096)
  stage(0, 0);
  asm volatile("s_waitcnt vmcnt(0)" ::: "memory");
  __builtin_amdgcn_s_barrier();
  for (int t2 = 0; t2 < NT; t2 += 2) {
    stage(1, (t2 + 1) << 6);                           // prefetch odd tile into buf1
    compute(0);
    asm volatile("s_waitcnt vmcnt(0)" ::: "memory");   // odd tile landed; all reads of buf0 done
    __builtin_amdgcn_s_barrier();
    if (t2 + 2 < NT) stage(0, (t2 + 2) << 6);          // prefetch next even tile into buf0
    compute(1);
    asm volatile("s_waitcnt vmcnt(0)" ::: "memory");
    __builtin_amdgcn_s_barrier();
  }

  #pragma unroll
  for (int n = 0; n < 4; ++n) {
    int col = bn + wc + (n << 4) + lr;
    float bval = bias[col];
    #pragma unroll
    for (int m = 0; m < 4; ++m) {
      #pragma unroll
      for (int j = 0; j < 4; ++j) {
        int row = bm + wr + (m << 4) + (g << 2) + j;   // C/D: col=lane&15, row=(lane>>4)*4+j
        float v = acc[m][n][j] + bval;
        size_t off = (size_t)row * N + col;
        if constexpr (EPI == 0)      ((_Float16*)out)[off] = (_Float16)v;
        else if constexpr (EPI == 1) ((float*)out)[off] = v;
        else if constexpr (EPI == 2) ((_Float16*)out)[off] = (_Float16)gelu_f(v);
        else                         ((float*)out)[off] += v;
      }
    }
  }
}

// ---------------- launch ----------------
extern "C" void kernel_launch(void* const* d_in, const int* in_sizes, int n_in,
                              void* d_out, int out_size, void* d_ws, size_t ws_size,
                              hipStream_t stream) {
  const float* ct   = (const float*)d_in[0];
  const float* rfq  = (const float*)d_in[1];
  // d_in[2..7]: ln1_s, ln1_b, wq, bq, wk, bk -- dead (softmax over kv_len=1 is identically 1)
  const float* wv   = (const float*)d_in[8];
  const float* bv   = (const float*)d_in[9];
  const float* wo   = (const float*)d_in[10];
  const float* bo   = (const float*)d_in[11];
  const float* ln2s = (const float*)d_in[12];
  const float* ln2b = (const float*)d_in[13];
  const float* w1   = (const float*)d_in[14];
  const float* b1   = (const float*)d_in[15];
  const float* w2   = (const float*)d_in[16];
  const float* b2   = (const float*)d_in[17];
  const float* lnfs = (const float*)d_in[18];
  const float* lnfb = (const float*)d_in[19];

  // fp32 residual stream lives in d_out (exactly M_ x D_ floats); final LN is in-place.
  float* x = (float*)d_out;

  // ---- workspace ----
  char* p = (char*)d_ws;
  auto alloc = [&](size_t bytes) { char* r = p; p += (bytes + 255) & ~(size_t)255; return r; };
  _Float16* kvh = (_Float16*)alloc((size_t)NTOK_ * D_ * 2);
  _Float16* Vh  = (_Float16*)alloc((size_t)NTOK_ * D_ * 2);
  float*    att = (float*)   alloc((size_t)NTOK_ * D_ * 4);
  _Float16* wvt = (_Float16*)alloc((size_t)D_ * D_ * 2);      // per-layer, reused
  _Float16* wot = (_Float16*)alloc((size_t)D_ * D_ * 2);
  _Float16* w1t = (_Float16*)alloc((size_t)D_ * DFF_ * 2);
  _Float16* w2t = (_Float16*)alloc((size_t)DFF_ * D_ * 2);
  size_t persist = (size_t)(p - (char*)d_ws);

  // MLP chunk: cap at 9216 so the per-chunk working set (H1 chunk 75MB + C 38MB
  // + weights 8MB) stays well inside the 256MB L3 -> gemm3's A re-reads L3-hit.
  int MC = 1152;
  const int cand[4] = {9216, 4608, 2304, 1152};
  for (int i = 0; i < 4; ++i) {
    size_t need = persist + ((size_t)cand[i] * D_ * 2 + 256) + ((size_t)cand[i] * DFF_ * 2 + 256) + 1024;
    if (need <= ws_size) { MC = cand[i]; break; }
  }
  _Float16* hh  = (_Float16*)alloc((size_t)MC * D_ * 2);      // LN2 output chunk
  _Float16* H1h = (_Float16*)alloc((size_t)MC * DFF_ * 2);    // gelu output chunk

  k_init_x<<<M_ * D_ / 4 / 256, 256, 0, stream>>>(x, rfq);
  k_cvt<<<NTOK_ * D_ / 4 / 256, 256, 0, stream>>>(ct, kvh);

  for (int l = 0; l < L_; ++l) {
    // per-layer weight transpose+convert (f32 -> f16, N x K layout)
    k_transpose_cvt<<<dim3(D_/32, D_/32), 256, 0, stream>>>(wv + (size_t)l*D_*D_,   wvt, D_, D_);
    k_transpose_cvt<<<dim3(D_/32, D_/32), 256, 0, stream>>>(wo + (size_t)l*D_*D_,   wot, D_, D_);
    k_transpose_cvt<<<dim3(DFF_/32, D_/32), 256, 0, stream>>>(w1 + (size_t)l*D_*DFF_, w1t, D_, DFF_);
    k_transpose_cvt<<<dim3(D_/32, DFF_/32), 256, 0, stream>>>(w2 + (size_t)l*DFF_*D_, w2t, DFF_, D_);

    // attention (collapsed, softmax over kv_len=1 == 1): att = (kv@wv+bv)@wo+bo ; x[n*16+r] += att[n]
    k_gemm<0><<<dim3(D_/128, NTOK_/128), 256, 0, stream>>>(kvh, wvt, bv + l*D_, Vh, NTOK_, D_, D_);
    k_gemm<1><<<dim3(D_/128, NTOK_/128), 256, 0, stream>>>(Vh,  wot, bo + l*D_, att, NTOK_, D_, D_);
    k_bcast_add<<<M_ * D_ / 4 / 256, 256, 0, stream>>>(x, att);

    // MLP, chunked over M (L3 locality + workspace fit)
    for (int m0 = 0; m0 < M_; m0 += MC) {
      k_ln<1><<<MC, 256, 0, stream>>>(x + (size_t)m0 * D_, ln2s + l*D_, ln2b + l*D_, hh);
      k_gemm<2><<<dim3(DFF_/128, MC/128), 256, 0, stream>>>(hh,  w1t, b1 + l*DFF_, H1h, MC, DFF_, D_);
      k_gemm<3><<<dim3(D_/128, MC/128), 256, 0, stream>>>(H1h, w2t, b2 + l*D_, x + (size_t)m0 * D_, MC, D_, DFF_);
    }
  }
  k_ln<0><<<M_, 256, 0, stream>>>(x, lnfs, lnfb, d_out);
}

// Round 5
// 1179.052 us; speedup vs baseline: 1.3098x; 1.3098x over previous
//
#include <hip/hip_runtime.h>
#include <hip/hip_bf16.h>
#include <math.h>

typedef float f4 __attribute__((ext_vector_type(4)));
typedef float f32x4 __attribute__((ext_vector_type(4)));
typedef _Float16 h4 __attribute__((ext_vector_type(4)));
typedef _Float16 h8 __attribute__((ext_vector_type(8)));

#define D_ 1024
#define DFF_ 4096
#define L_ 2
#define RF_ 16
#define NTOK_ 1152            // B * NC = 32*36
#define M_ 18432              // NTOK_ * RF_

__device__ __forceinline__ void gload_lds16(const void* g, void* l) {
  __builtin_amdgcn_global_load_lds((const __attribute__((address_space(1))) void*)g,
                                   (__attribute__((address_space(3))) void*)l, 16, 0, 0);
}

// exact-GELU via A&S 7.1.26 erf poly (|err| <= 1.5e-7), cheap VALU vs libm erff
__device__ __forceinline__ float gelu_f(float x) {
  float z = fabsf(x) * 0.70710678118654752f;
  float t = 1.0f / (1.0f + 0.3275911f * z);
  float poly = t * (0.254829592f + t * (-0.284496736f + t * (1.421413741f +
               t * (-1.453152027f + t * 1.061405429f))));
  float erfz = 1.0f - poly * __expf(-z * z);
  erfz = copysignf(erfz, x);
  return 0.5f * x * (1.0f + erfz);
}

// ---------------- elementwise ----------------
__global__ __launch_bounds__(256) void k_init_x(float* __restrict__ x, const float* __restrict__ rfq) {
  int i = blockIdx.x * 256 + threadIdx.x;   // float4 index
  int c = i & 255;                          // D/4 = 256
  int m = i >> 8;
  ((f4*)x)[i] = ((const f4*)rfq)[((m & 15) << 8) | c];   // row m -> rf row m%16
}

__global__ __launch_bounds__(256) void k_cvt(const float* __restrict__ in, _Float16* __restrict__ out) {
  int i = blockIdx.x * 256 + threadIdx.x;
  f4 v = ((const f4*)in)[i];
  ((h4*)out)[i] = __builtin_convertvector(v, h4);
}

__global__ __launch_bounds__(256) void k_bcast_add(float* __restrict__ x, const float* __restrict__ att) {
  int i = blockIdx.x * 256 + threadIdx.x;
  int c = i & 255;
  int m = i >> 8;
  int n = m >> 4;                           // m / RF
  f4 v = ((f4*)x)[i];
  f4 a = ((const f4*)att)[(n << 8) | c];
  ((f4*)x)[i] = v + a;
}

// W (R x C, f32, row-major) -> WT (C x R, f16)
__global__ __launch_bounds__(256) void k_transpose_cvt(const float* __restrict__ W, _Float16* __restrict__ WT,
                                                       int R, int C) {
  __shared__ float t[32][33];
  int c0 = blockIdx.x * 32, r0 = blockIdx.y * 32;
  int cc = threadIdx.x & 31, rr = threadIdx.x >> 5;   // rr: 0..7
  #pragma unroll
  for (int p = 0; p < 32; p += 8)
    t[rr + p][cc] = W[(size_t)(r0 + rr + p) * C + (c0 + cc)];
  __syncthreads();
  #pragma unroll
  for (int p = 0; p < 32; p += 8)
    WT[(size_t)(c0 + rr + p) * R + (r0 + cc)] = (_Float16)t[cc][rr + p];
}

// ---------------- layernorm ----------------
__device__ inline float block_sum256(float v) {
  __shared__ float red[4];
  #pragma unroll
  for (int o = 32; o > 0; o >>= 1) v += __shfl_down(v, o);
  int w = threadIdx.x >> 6;
  if ((threadIdx.x & 63) == 0) red[w] = v;
  __syncthreads();
  float r = red[0] + red[1] + red[2] + red[3];
  __syncthreads();
  return r;
}

template<int F16OUT>
__global__ __launch_bounds__(256) void k_ln(const float* __restrict__ x, const float* __restrict__ s,
                                            const float* __restrict__ b, void* __restrict__ out) {
  size_t row = blockIdx.x;
  int t = threadIdx.x;
  f4 v = ((const f4*)(x + row * D_))[t];
  float mean = block_sum256(v.x + v.y + v.z + v.w) * (1.0f / D_);
  f4 d = v - mean;
  float var = block_sum256(d.x*d.x + d.y*d.y + d.z*d.z + d.w*d.w) * (1.0f / D_);
  float rstd = rsqrtf(var + 1e-5f);
  f4 sc = ((const f4*)s)[t];
  f4 bb = ((const f4*)b)[t];
  f4 r = d * rstd * sc + bb;
  if (F16OUT) ((h4*)out)[row * (D_/4) + t] = __builtin_convertvector(r, h4);
  else        ((f4*)out)[row * (D_/4) + t] = r;
}

// ---------------- GEMM:  C(MxN) = A(MxK,f16) @ Bt(NxK,f16)^T + bias ----------------
// m97 structure (verified best at 128^2 tile): single-buffered [128][64] LDS,
// global_load_lds width=16, BK=64, both-sides XOR swizzle (0 bank conflicts,
// verified round 3). Occupancy ~4 blocks/CU gives implicit wave-level overlap
// (m114) -- explicit dbuf regressed (round 4 == m99/m100 result).
// EPI: 0 -> f16 store, 1 -> f32 store, 2 -> gelu f16 store, 3 -> += into f32
template<int EPI>
__global__ __launch_bounds__(256) void k_gemm(const _Float16* __restrict__ A,
                                              const _Float16* __restrict__ Bt,
                                              const float* __restrict__ bias,
                                              void* __restrict__ out,
                                              int M, int N, int K) {
  __shared__ __align__(16) _Float16 As[128][64];
  __shared__ __align__(16) _Float16 Bs[128][64];
  const int tid = threadIdx.x;
  const int lane = tid & 63;
  const int w = tid >> 6;

  // T1: XCD chunked-contiguous block swizzle (all our grids have nwg % 8 == 0)
  const unsigned gdx = gridDim.x;
  const unsigned nwg = gdx * gridDim.y;
  unsigned bid = blockIdx.y * gdx + blockIdx.x;
  if ((nwg & 7u) == 0u) bid = (bid & 7u) * (nwg >> 3) + (bid >> 3);
  const int bm = (int)(bid / gdx) << 7;
  const int bn = (int)(bid % gdx) << 7;

  const int wr = (w >> 1) << 6;       // wave row offset in tile (0/64)
  const int wc = (w & 1) << 6;        // wave col offset (0/64)
  const int g = lane >> 4;            // 0..3
  const int lr = lane & 15;
  const int x7 = lr & 7;              // read-side swizzle key (row&7 == lr&7)
  const int srow = lane >> 3;         // staging row within 8-row group
  const int scl8 = (((lane & 7) ^ (srow & 7)) << 3);   // inverse-swizzled src col (halves)

  f32x4 acc[4][4];
  #pragma unroll
  for (int m = 0; m < 4; ++m)
    #pragma unroll
    for (int n = 0; n < 4; ++n)
      acc[m][n] = (f32x4){0.f, 0.f, 0.f, 0.f};

  const _Float16* Ab = A + (size_t)bm * K;
  const _Float16* Bb = Bt + (size_t)bn * K;

  for (int kt = 0; kt < K; kt += 64) {
    #pragma unroll
    for (int p = 0; p < 4; ++p) {
      int r0 = ((w << 2) + p) << 3;                    // wave-uniform LDS base row
      int r = r0 + srow;
      gload_lds16(Ab + (size_t)r * K + kt + scl8, &As[r0][0]);
      gload_lds16(Bb + (size_t)r * K + kt + scl8, &Bs[r0][0]);
    }
    __syncthreads();                                   // drains vmcnt before LDS reads
    #pragma unroll
    for (int kk8 = 0; kk8 < 8; kk8 += 4) {             // two K=32 sub-steps
      h8 af[4], bf[4];
      const int c8 = ((kk8 + g) ^ x7) << 3;            // swizzled read slot (halves)
      #pragma unroll
      for (int m = 0; m < 4; ++m) af[m] = *(const h8*)(&As[wr + (m << 4) + lr][c8]);
      #pragma unroll
      for (int n = 0; n < 4; ++n) bf[n] = *(const h8*)(&Bs[wc + (n << 4) + lr][c8]);
      #pragma unroll
      for (int m = 0; m < 4; ++m)
        #pragma unroll
        for (int n = 0; n < 4; ++n)
          acc[m][n] = __builtin_amdgcn_mfma_f32_16x16x32_f16(af[m], bf[n], acc[m][n], 0, 0, 0);
    }
    __syncthreads();
  }

  #pragma unroll
  for (int n = 0; n < 4; ++n) {
    int col = bn + wc + (n << 4) + lr;
    float bval = bias[col];
    #pragma unroll
    for (int m = 0; m < 4; ++m) {
      #pragma unroll
      for (int j = 0; j < 4; ++j) {
        int row = bm + wr + (m << 4) + (g << 2) + j;   // C/D: col=lane&15, row=(lane>>4)*4+j
        float v = acc[m][n][j] + bval;
        size_t off = (size_t)row * N + col;
        if constexpr (EPI == 0)      ((_Float16*)out)[off] = (_Float16)v;
        else if constexpr (EPI == 1) ((float*)out)[off] = v;
        else if constexpr (EPI == 2) ((_Float16*)out)[off] = (_Float16)gelu_f(v);
        else                         ((float*)out)[off] += v;
      }
    }
  }
}

// ---------------- launch ----------------
extern "C" void kernel_launch(void* const* d_in, const int* in_sizes, int n_in,
                              void* d_out, int out_size, void* d_ws, size_t ws_size,
                              hipStream_t stream) {
  const float* ct   = (const float*)d_in[0];
  const float* rfq  = (const float*)d_in[1];
  // d_in[2..7]: ln1_s, ln1_b, wq, bq, wk, bk -- dead (softmax over kv_len=1 is identically 1)
  const float* wv   = (const float*)d_in[8];
  const float* bv   = (const float*)d_in[9];
  const float* wo   = (const float*)d_in[10];
  const float* bo   = (const float*)d_in[11];
  const float* ln2s = (const float*)d_in[12];
  const float* ln2b = (const float*)d_in[13];
  const float* w1   = (const float*)d_in[14];
  const float* b1   = (const float*)d_in[15];
  const float* w2   = (const float*)d_in[16];
  const float* b2   = (const float*)d_in[17];
  const float* lnfs = (const float*)d_in[18];
  const float* lnfb = (const float*)d_in[19];

  // fp32 residual stream lives in d_out (exactly M_ x D_ floats); final LN is in-place.
  float* x = (float*)d_out;

  // ---- workspace ----
  char* p = (char*)d_ws;
  auto alloc = [&](size_t bytes) { char* r = p; p += (bytes + 255) & ~(size_t)255; return r; };
  _Float16* kvh = (_Float16*)alloc((size_t)NTOK_ * D_ * 2);
  _Float16* Vh  = (_Float16*)alloc((size_t)NTOK_ * D_ * 2);
  float*    att = (float*)   alloc((size_t)NTOK_ * D_ * 4);
  _Float16* wvt = (_Float16*)alloc((size_t)D_ * D_ * 2);      // per-layer, reused
  _Float16* wot = (_Float16*)alloc((size_t)D_ * D_ * 2);
  _Float16* w1t = (_Float16*)alloc((size_t)D_ * DFF_ * 2);
  _Float16* w2t = (_Float16*)alloc((size_t)DFF_ * D_ * 2);
  size_t persist = (size_t)(p - (char*)d_ws);

  // MLP chunk: cap at 9216 so the per-chunk working set (~121 MB, verified at
  // FETCH ideal in round 4) stays inside the 256MB L3 -> A-panel stages L3-hit.
  int MC = 1152;
  const int cand[4] = {9216, 4608, 2304, 1152};
  for (int i = 0; i < 4; ++i) {
    size_t need = persist + ((size_t)cand[i] * D_ * 2 + 256) + ((size_t)cand[i] * DFF_ * 2 + 256) + 1024;
    if (need <= ws_size) { MC = cand[i]; break; }
  }
  _Float16* hh  = (_Float16*)alloc((size_t)MC * D_ * 2);      // LN2 output chunk
  _Float16* H1h = (_Float16*)alloc((size_t)MC * DFF_ * 2);    // gelu output chunk

  k_init_x<<<M_ * D_ / 4 / 256, 256, 0, stream>>>(x, rfq);
  k_cvt<<<NTOK_ * D_ / 4 / 256, 256, 0, stream>>>(ct, kvh);

  for (int l = 0; l < L_; ++l) {
    // per-layer weight transpose+convert (f32 -> f16, N x K layout)
    k_transpose_cvt<<<dim3(D_/32, D_/32), 256, 0, stream>>>(wv + (size_t)l*D_*D_,   wvt, D_, D_);
    k_transpose_cvt<<<dim3(D_/32, D_/32), 256, 0, stream>>>(wo + (size_t)l*D_*D_,   wot, D_, D_);
    k_transpose_cvt<<<dim3(DFF_/32, D_/32), 256, 0, stream>>>(w1 + (size_t)l*D_*DFF_, w1t, D_, DFF_);
    k_transpose_cvt<<<dim3(D_/32, DFF_/32), 256, 0, stream>>>(w2 + (size_t)l*DFF_*D_, w2t, DFF_, D_);

    // attention (collapsed, softmax over kv_len=1 == 1): att = (kv@wv+bv)@wo+bo ; x[n*16+r] += att[n]
    k_gemm<0><<<dim3(D_/128, NTOK_/128), 256, 0, stream>>>(kvh, wvt, bv + l*D_, Vh, NTOK_, D_, D_);
    k_gemm<1><<<dim3(D_/128, NTOK_/128), 256, 0, stream>>>(Vh,  wot, bo + l*D_, att, NTOK_, D_, D_);
    k_bcast_add<<<M_ * D_ / 4 / 256, 256, 0, stream>>>(x, att);

    // MLP, chunked over M (L3 locality + workspace fit)
    for (int m0 = 0; m0 < M_; m0 += MC) {
      k_ln<1><<<MC, 256, 0, stream>>>(x + (size_t)m0 * D_, ln2s + l*D_, ln2b + l*D_, hh);
      k_gemm<2><<<dim3(DFF_/128, MC/128), 256, 0, stream>>>(hh,  w1t, b1 + l*DFF_, H1h, MC, DFF_, D_);
      k_gemm<3><<<dim3(D_/128, MC/128), 256, 0, stream>>>(H1h, w2t, b2 + l*D_, x + (size_t)m0 * D_, MC, D_, DFF_);
    }
  }
  k_ln<0><<<M_, 256, 0, stream>>>(x, lnfs, lnfb, d_out);
}

// Round 6
// 1032.476 us; speedup vs baseline: 1.4957x; 1.1420x over previous
//
#include <hip/hip_runtime.h>
#include <hip/hip_bf16.h>
#include <math.h>

typedef float f4 __attribute__((ext_vector_type(4)));
typedef float f32x4 __attribute__((ext_vector_type(4)));
typedef _Float16 h4 __attribute__((ext_vector_type(4)));
typedef _Float16 h8 __attribute__((ext_vector_type(8)));

#define D_ 1024
#define DFF_ 4096
#define L_ 2
#define RF_ 16
#define NTOK_ 1152            // B * NC = 32*36
#define M_ 18432              // NTOK_ * RF_
#define XROWS_ 1280           // 1152 att-rows + 16 rfq-rows + s-row + b-row + pad

__device__ __forceinline__ void gload_lds16(const void* g, void* l) {
  __builtin_amdgcn_global_load_lds((const __attribute__((address_space(1))) void*)g,
                                   (__attribute__((address_space(3))) void*)l, 16, 0, 0);
}

// exact-GELU via A&S 7.1.26 erf poly (|err| <= 1.5e-7)
__device__ __forceinline__ float gelu_f(float x) {
  float z = fabsf(x) * 0.70710678118654752f;
  float t = 1.0f / (1.0f + 0.3275911f * z);
  float poly = t * (0.254829592f + t * (-0.284496736f + t * (1.421413741f +
               t * (-1.453152027f + t * 1.061405429f))));
  float erfz = 1.0f - poly * __expf(-z * z);
  erfz = copysignf(erfz, x);
  return 0.5f * x * (1.0f + erfz);
}

// ---------------- elementwise ----------------
__global__ __launch_bounds__(256) void k_init_x(float* __restrict__ x, const float* __restrict__ rfq) {
  int i = blockIdx.x * 256 + threadIdx.x;   // float4 index
  int c = i & 255;                          // D/4 = 256
  int m = i >> 8;
  ((f4*)x)[i] = ((const f4*)rfq)[((m & 15) << 8) | c];
}

__global__ __launch_bounds__(256) void k_cvt(const float* __restrict__ in, _Float16* __restrict__ out) {
  int i = blockIdx.x * 256 + threadIdx.x;
  f4 v = ((const f4*)in)[i];
  ((h4*)out)[i] = __builtin_convertvector(v, h4);
}

__global__ __launch_bounds__(256) void k_bcast_add(float* __restrict__ x, const float* __restrict__ att) {
  int i = blockIdx.x * 256 + threadIdx.x;
  int c = i & 255;
  int m = i >> 8;
  int n = m >> 4;
  f4 v = ((f4*)x)[i];
  f4 a = ((const f4*)att)[(n << 8) | c];
  ((f4*)x)[i] = v + a;
}

// X matrix for layer-0 MLP decomposition: rows 0..1151 = att[n]*s, 1152..1167 = rfq[r]*s,
// 1168 = s, 1169 = b, 1170..1279 = 0
__global__ __launch_bounds__(256) void k_build_X(const float* __restrict__ att, const float* __restrict__ rfq,
                                                 const float* __restrict__ s, const float* __restrict__ b,
                                                 _Float16* __restrict__ X) {
  int i = blockIdx.x * 256 + threadIdx.x;   // f4/h4 index over XROWS_*256
  int c = i & 255;
  int row = i >> 8;
  f4 sv = ((const f4*)s)[c];
  f4 v;
  if (row < 1152)      v = ((const f4*)att)[(row << 8) | c] * sv;
  else if (row < 1168) v = ((const f4*)rfq)[((row - 1152) << 8) | c] * sv;
  else if (row == 1168) v = sv;
  else if (row == 1169) v = ((const f4*)b)[c];
  else                 v = (f4){0.f, 0.f, 0.f, 0.f};
  ((h4*)X)[i] = __builtin_convertvector(v, h4);
}

// W (R x C, f32, row-major) -> WT (C x R, f16)
__global__ __launch_bounds__(256) void k_transpose_cvt(const float* __restrict__ W, _Float16* __restrict__ WT,
                                                       int R, int C) {
  __shared__ float t[32][33];
  int c0 = blockIdx.x * 32, r0 = blockIdx.y * 32;
  int cc = threadIdx.x & 31, rr = threadIdx.x >> 5;
  #pragma unroll
  for (int p = 0; p < 32; p += 8)
    t[rr + p][cc] = W[(size_t)(r0 + rr + p) * C + (c0 + cc)];
  __syncthreads();
  #pragma unroll
  for (int p = 0; p < 32; p += 8)
    WT[(size_t)(c0 + rr + p) * R + (r0 + cc)] = (_Float16)t[cc][rr + p];
}

// ---------------- reductions ----------------
__device__ inline float block_sum256(float v) {
  __shared__ float red[4];
  #pragma unroll
  for (int o = 32; o > 0; o >>= 1) v += __shfl_down(v, o);
  int w = threadIdx.x >> 6;
  if ((threadIdx.x & 63) == 0) red[w] = v;
  __syncthreads();
  float r = red[0] + red[1] + red[2] + red[3];
  __syncthreads();
  return r;
}

// per-n scalars for layer-0 LN decomposition: out[n*24+0]=Sum(a), [1]=Sum(a^2), [2+r]=dot(a,q_r)
__global__ __launch_bounds__(256) void k_scal_n(const float* __restrict__ att, const float* __restrict__ rfq,
                                                float* __restrict__ out) {
  int n = blockIdx.x;
  int t = threadIdx.x;
  f4 av = ((const f4*)(att + (size_t)n * D_))[t];
  float s1 = block_sum256(av.x + av.y + av.z + av.w);
  float s2 = block_sum256(av.x*av.x + av.y*av.y + av.z*av.z + av.w*av.w);
  if (t == 0) { out[n*24+0] = s1; out[n*24+1] = s2; }
  #pragma unroll
  for (int r = 0; r < RF_; ++r) {
    f4 qv = ((const f4*)(rfq + (size_t)r * D_))[t];
    float d = block_sum256(av.x*qv.x + av.y*qv.y + av.z*qv.z + av.w*qv.w);
    if (t == 0) out[n*24+2+r] = d;
  }
}

// per-r scalars: out[r*2+0]=Sum(q), [1]=Sum(q^2)
__global__ __launch_bounds__(256) void k_scal_q(const float* __restrict__ rfq, float* __restrict__ out) {
  int r = blockIdx.x;
  int t = threadIdx.x;
  f4 qv = ((const f4*)(rfq + (size_t)r * D_))[t];
  float s1 = block_sum256(qv.x + qv.y + qv.z + qv.w);
  float s2 = block_sum256(qv.x*qv.x + qv.y*qv.y + qv.z*qv.z + qv.w*qv.w);
  if (t == 0) { out[r*2+0] = s1; out[r*2+1] = s2; }
}

// H1[m,:] = gelu( rstd*(P_a[n] + P_q[r] - mu*P_s) + P_b + b1 ),  m=m0+blk, n=m>>4, r=m&15
__global__ __launch_bounds__(256) void k_combine_gelu(const float* __restrict__ P,
                                                      const float* __restrict__ scn,
                                                      const float* __restrict__ scq,
                                                      const float* __restrict__ b1,
                                                      _Float16* __restrict__ H1, int m0) {
  int m = m0 + blockIdx.x;
  int n = m >> 4, r = m & 15;
  float Sa = scn[n*24+0], Saa = scn[n*24+1], dq = scn[n*24+2+r];
  float Sq = scq[r*2+0], Sqq = scq[r*2+1];
  float mu  = (Sa + Sq) * (1.0f / D_);
  float ex2 = (Saa + 2.0f*dq + Sqq) * (1.0f / D_);
  float rstd = rsqrtf(ex2 - mu*mu + 1e-5f);
  const f4* Pa = (const f4*)(P + (size_t)n * DFF_);
  const f4* Pq = (const f4*)(P + (size_t)(1152 + r) * DFF_);
  const f4* Ps = (const f4*)(P + (size_t)1168 * DFF_);
  const f4* Pb = (const f4*)(P + (size_t)1169 * DFF_);
  const f4* B1 = (const f4*)b1;
  h4* out = (h4*)(H1 + (size_t)blockIdx.x * DFF_);
  #pragma unroll
  for (int it = 0; it < 4; ++it) {
    int j = threadIdx.x + (it << 8);          // f4 col, 0..1023
    f4 hp = (Pa[j] + Pq[j] - mu * Ps[j]) * rstd + Pb[j] + B1[j];
    h4 o;
    o.x = (_Float16)gelu_f(hp.x); o.y = (_Float16)gelu_f(hp.y);
    o.z = (_Float16)gelu_f(hp.z); o.w = (_Float16)gelu_f(hp.w);
    out[j] = o;
  }
}

// ---------------- layernorm ----------------
template<int F16OUT>
__global__ __launch_bounds__(256) void k_ln(const float* __restrict__ x, const float* __restrict__ s,
                                            const float* __restrict__ b, void* __restrict__ out) {
  size_t row = blockIdx.x;
  int t = threadIdx.x;
  f4 v = ((const f4*)(x + row * D_))[t];
  float mean = block_sum256(v.x + v.y + v.z + v.w) * (1.0f / D_);
  f4 d = v - mean;
  float var = block_sum256(d.x*d.x + d.y*d.y + d.z*d.z + d.w*d.w) * (1.0f / D_);
  float rstd = rsqrtf(var + 1e-5f);
  f4 sc = ((const f4*)s)[t];
  f4 bb = ((const f4*)b)[t];
  f4 r = d * rstd * sc + bb;
  if (F16OUT) ((h4*)out)[row * (D_/4) + t] = __builtin_convertvector(r, h4);
  else        ((f4*)out)[row * (D_/4) + t] = r;
}

// ---------------- GEMM:  C(MxN) = A(MxK,f16) @ Bt(NxK,f16)^T + bias ----------------
// m97 structure (verified best at 128^2 tile, rounds 3-5): single-buffered
// [128][64] LDS, global_load_lds w=16, BK=64, both-sides XOR swizzle (0 conflicts).
// EPI: 0 f16 store, 1 f32 store, 2 gelu f16 store, 3 += into f32, 4 f32 store no bias
template<int EPI>
__global__ __launch_bounds__(256) void k_gemm(const _Float16* __restrict__ A,
                                              const _Float16* __restrict__ Bt,
                                              const float* __restrict__ bias,
                                              void* __restrict__ out,
                                              int M, int N, int K) {
  __shared__ __align__(16) _Float16 As[128][64];
  __shared__ __align__(16) _Float16 Bs[128][64];
  const int tid = threadIdx.x;
  const int lane = tid & 63;
  const int w = tid >> 6;

  const unsigned gdx = gridDim.x;
  const unsigned nwg = gdx * gridDim.y;
  unsigned bid = blockIdx.y * gdx + blockIdx.x;
  if ((nwg & 7u) == 0u) bid = (bid & 7u) * (nwg >> 3) + (bid >> 3);
  const int bm = (int)(bid / gdx) << 7;
  const int bn = (int)(bid % gdx) << 7;

  const int wr = (w >> 1) << 6;
  const int wc = (w & 1) << 6;
  const int g = lane >> 4;
  const int lr = lane & 15;
  const int x7 = lr & 7;
  const int srow = lane >> 3;
  const int scl8 = (((lane & 7) ^ (srow & 7)) << 3);

  f32x4 acc[4][4];
  #pragma unroll
  for (int m = 0; m < 4; ++m)
    #pragma unroll
    for (int n = 0; n < 4; ++n)
      acc[m][n] = (f32x4){0.f, 0.f, 0.f, 0.f};

  const _Float16* Ab = A + (size_t)bm * K;
  const _Float16* Bb = Bt + (size_t)bn * K;

  for (int kt = 0; kt < K; kt += 64) {
    #pragma unroll
    for (int p = 0; p < 4; ++p) {
      int r0 = ((w << 2) + p) << 3;
      int r = r0 + srow;
      gload_lds16(Ab + (size_t)r * K + kt + scl8, &As[r0][0]);
      gload_lds16(Bb + (size_t)r * K + kt + scl8, &Bs[r0][0]);
    }
    __syncthreads();
    #pragma unroll
    for (int kk8 = 0; kk8 < 8; kk8 += 4) {
      h8 af[4], bf[4];
      const int c8 = ((kk8 + g) ^ x7) << 3;
      #pragma unroll
      for (int m = 0; m < 4; ++m) af[m] = *(const h8*)(&As[wr + (m << 4) + lr][c8]);
      #pragma unroll
      for (int n = 0; n < 4; ++n) bf[n] = *(const h8*)(&Bs[wc + (n << 4) + lr][c8]);
      #pragma unroll
      for (int m = 0; m < 4; ++m)
        #pragma unroll
        for (int n = 0; n < 4; ++n)
          acc[m][n] = __builtin_amdgcn_mfma_f32_16x16x32_f16(af[m], bf[n], acc[m][n], 0, 0, 0);
    }
    __syncthreads();
  }

  #pragma unroll
  for (int n = 0; n < 4; ++n) {
    int col = bn + wc + (n << 4) + lr;
    float bval = (EPI == 4) ? 0.0f : bias[col];
    #pragma unroll
    for (int m = 0; m < 4; ++m) {
      #pragma unroll
      for (int j = 0; j < 4; ++j) {
        int row = bm + wr + (m << 4) + (g << 2) + j;
        float v = acc[m][n][j] + bval;
        size_t off = (size_t)row * N + col;
        if constexpr (EPI == 0)      ((_Float16*)out)[off] = (_Float16)v;
        else if constexpr (EPI == 1) ((float*)out)[off] = v;
        else if constexpr (EPI == 2) ((_Float16*)out)[off] = (_Float16)gelu_f(v);
        else if constexpr (EPI == 3) ((float*)out)[off] += v;
        else                         ((float*)out)[off] = v;
      }
    }
  }
}

// ---------------- launch ----------------
extern "C" void kernel_launch(void* const* d_in, const int* in_sizes, int n_in,
                              void* d_out, int out_size, void* d_ws, size_t ws_size,
                              hipStream_t stream) {
  const float* ct   = (const float*)d_in[0];
  const float* rfq  = (const float*)d_in[1];
  // d_in[2..7]: ln1_s, ln1_b, wq, bq, wk, bk -- dead (softmax over kv_len=1 is identically 1)
  const float* wv   = (const float*)d_in[8];
  const float* bv   = (const float*)d_in[9];
  const float* wo   = (const float*)d_in[10];
  const float* bo   = (const float*)d_in[11];
  const float* ln2s = (const float*)d_in[12];
  const float* ln2b = (const float*)d_in[13];
  const float* w1   = (const float*)d_in[14];
  const float* b1   = (const float*)d_in[15];
  const float* w2   = (const float*)d_in[16];
  const float* b2   = (const float*)d_in[17];
  const float* lnfs = (const float*)d_in[18];
  const float* lnfb = (const float*)d_in[19];

  float* x = (float*)d_out;   // fp32 residual stream in d_out; final LN in-place

  // ---- workspace ----
  char* p = (char*)d_ws;
  auto alloc = [&](size_t bytes) { char* r = p; p += (bytes + 255) & ~(size_t)255; return r; };
  _Float16* kvh = (_Float16*)alloc((size_t)NTOK_ * D_ * 2);
  _Float16* Vh  = (_Float16*)alloc((size_t)NTOK_ * D_ * 2);
  float*    att = (float*)   alloc((size_t)NTOK_ * D_ * 4);
  _Float16* wvt = (_Float16*)alloc((size_t)D_ * D_ * 2);
  _Float16* wot = (_Float16*)alloc((size_t)D_ * D_ * 2);
  _Float16* w1t = (_Float16*)alloc((size_t)D_ * DFF_ * 2);
  _Float16* w2t = (_Float16*)alloc((size_t)DFF_ * D_ * 2);
  _Float16* Xh  = (_Float16*)alloc((size_t)XROWS_ * D_ * 2);   // layer-0 LN-decomp input
  float*    P   = (float*)   alloc((size_t)XROWS_ * DFF_ * 4); // X @ w1
  float*    scn = (float*)   alloc((size_t)NTOK_ * 24 * 4);
  float*    scq = (float*)   alloc((size_t)RF_ * 2 * 4);
  size_t persist = (size_t)(p - (char*)d_ws);

  int MC = 1152;
  const int cand[4] = {9216, 4608, 2304, 1152};
  for (int i = 0; i < 4; ++i) {
    size_t need = persist + ((size_t)cand[i] * D_ * 2 + 256) + ((size_t)cand[i] * DFF_ * 2 + 256) + 1024;
    if (need <= ws_size) { MC = cand[i]; break; }
  }
  _Float16* hh  = (_Float16*)alloc((size_t)MC * D_ * 2);
  _Float16* H1h = (_Float16*)alloc((size_t)MC * DFF_ * 2);

  k_init_x<<<M_ * D_ / 4 / 256, 256, 0, stream>>>(x, rfq);
  k_cvt<<<NTOK_ * D_ / 4 / 256, 256, 0, stream>>>(ct, kvh);

  for (int l = 0; l < L_; ++l) {
    k_transpose_cvt<<<dim3(D_/32, D_/32), 256, 0, stream>>>(wv + (size_t)l*D_*D_,   wvt, D_, D_);
    k_transpose_cvt<<<dim3(D_/32, D_/32), 256, 0, stream>>>(wo + (size_t)l*D_*D_,   wot, D_, D_);
    k_transpose_cvt<<<dim3(DFF_/32, D_/32), 256, 0, stream>>>(w1 + (size_t)l*D_*DFF_, w1t, D_, DFF_);
    k_transpose_cvt<<<dim3(D_/32, DFF_/32), 256, 0, stream>>>(w2 + (size_t)l*DFF_*D_, w2t, DFF_, D_);

    // attention (collapsed): att = (kv@wv+bv)@wo+bo ; x[n*16+r] += att[n]
    k_gemm<0><<<dim3(D_/128, NTOK_/128), 256, 0, stream>>>(kvh, wvt, bv + l*D_, Vh, NTOK_, D_, D_);
    k_gemm<1><<<dim3(D_/128, NTOK_/128), 256, 0, stream>>>(Vh,  wot, bo + l*D_, att, NTOK_, D_, D_);
    k_bcast_add<<<M_ * D_ / 4 / 256, 256, 0, stream>>>(x, att);

    if (l == 0) {
      // x[n,r] = att[n] + rfq[r] EXACTLY -> LN+gemm1 decomposes:
      // h@w1+b1 = rstd[n,r]*(P_a[n] + P_q[r] - mu[n,r]*P_s) + P_b + b1
      k_build_X<<<XROWS_ * D_ / 4 / 256, 256, 0, stream>>>(att, rfq, ln2s, ln2b, Xh);
      k_scal_n<<<NTOK_, 256, 0, stream>>>(att, rfq, scn);
      k_scal_q<<<RF_, 256, 0, stream>>>(rfq, scq);
      k_gemm<4><<<dim3(DFF_/128, XROWS_/128), 256, 0, stream>>>(Xh, w1t, nullptr, P, XROWS_, DFF_, D_);
      for (int m0 = 0; m0 < M_; m0 += MC) {
        k_combine_gelu<<<MC, 256, 0, stream>>>(P, scn, scq, b1, H1h, m0);
        k_gemm<3><<<dim3(D_/128, MC/128), 256, 0, stream>>>(H1h, w2t, b2, x + (size_t)m0 * D_, MC, D_, DFF_);
      }
    } else {
      for (int m0 = 0; m0 < M_; m0 += MC) {
        k_ln<1><<<MC, 256, 0, stream>>>(x + (size_t)m0 * D_, ln2s + l*D_, ln2b + l*D_, hh);
        k_gemm<2><<<dim3(DFF_/128, MC/128), 256, 0, stream>>>(hh,  w1t, b1 + l*DFF_, H1h, MC, DFF_, D_);
        k_gemm<3><<<dim3(D_/128, MC/128), 256, 0, stream>>>(H1h, w2t, b2 + l*D_, x + (size_t)m0 * D_, MC, D_, DFF_);
      }
    }
  }
  k_ln<0><<<M_, 256, 0, stream>>>(x, lnfs, lnfb, d_out);
}